// Round 2
// baseline (1101.911 us; speedup 1.0000x reference)
//
#include <hip/hip_runtime.h>

// SparseConvolutionDownsample: rulebook sparse conv (gather -> GEMM -> scatter-add)
// + BatchNorm over active sites + LeakyReLU(0.333).
//
// Fixed problem constants: C_IN=64, C_OUT=128, K=4, P=262144, n_out=262144.
//
// R2: sF tile stored as bf16 (rounded) -> LDS 65KB -> 49KB -> 3 blocks/CU
// (occupancy 21.8% -> ~33%). W stays fp32 in LDS. Paired bf16 reads halve
// the f-read count in the inner loop.

#define C_IN   64
#define C_OUT  128
#define KOFF   4
#define TILE_P 128
#define SF_LD  66            // bf16 elements per row: 132B stride -> 8-row strided reads hit 4 distinct banks
#define BN_EPS 1e-4f
#define LEAK   0.333f

__device__ inline unsigned short f32_to_bf16_rn(float x) {
    unsigned int b = __float_as_uint(x);
    unsigned int r = (b + 0x7FFFu + ((b >> 16) & 1u)) >> 16;
    return (unsigned short)r;
}

// ---------------------------------------------------------------------------
// Kernel 1: per-offset gather + 128x128 GEMM tile + atomic scatter-add.
// Block = 256 threads. tx = tid&15 -> cols {tx + 16j}, ty = tid>>4 -> rows
// {8ty..8ty+7}. Each thread: 8x8 fp32 accumulators.
// ---------------------------------------------------------------------------
__global__ __launch_bounds__(256) void scatter_gemm_kernel(
    const float* __restrict__ feats, const float* __restrict__ W,
    const int* __restrict__ in_idx, const int* __restrict__ out_idx,
    float* __restrict__ out, int P)
{
    __shared__ float sW[C_IN][C_OUT];              // 32 KB
    __shared__ unsigned short sF[TILE_P][SF_LD];   // 16.9 KB bf16

    const int tid = threadIdx.x;
    const int k  = blockIdx.y;
    const int p0 = blockIdx.x * TILE_P;

    // Stage W[k] (64x128 = 2048 float4) -> LDS, coalesced.
    const float4* Wk4 = (const float4*)(W + (size_t)k * C_IN * C_OUT);
    float4* sW4 = (float4*)&sW[0][0];
    #pragma unroll
    for (int i = tid; i < C_IN * C_OUT / 4; i += 256)
        sW4[i] = Wk4[i];

    // Stage gathered feats rows: 128 rows x 16 float4, converted to bf16.
    // 16 consecutive threads load one row (coalesced 256B).
    for (int i = tid; i < TILE_P * (C_IN / 4); i += 256) {
        int r  = i >> 4;
        int c4 = i & 15;
        int src = in_idx[(size_t)k * P + p0 + r];
        float4 v = ((const float4*)(feats + (size_t)src * C_IN))[c4];
        unsigned int lo = (unsigned int)f32_to_bf16_rn(v.x) | ((unsigned int)f32_to_bf16_rn(v.y) << 16);
        unsigned int hi = (unsigned int)f32_to_bf16_rn(v.z) | ((unsigned int)f32_to_bf16_rn(v.w) << 16);
        unsigned int* dst = (unsigned int*)&sF[r][c4 * 4];   // 8B-aligned (c4*4 ushorts), row stride 132B (4B mult)
        dst[0] = lo;
        dst[1] = hi;
    }
    __syncthreads();

    const int tx = tid & 15;   // col base: tx + 16*j
    const int ty = tid >> 4;   // row base: 8*ty + r

    float acc[8][8];
    #pragma unroll
    for (int r = 0; r < 8; ++r)
        #pragma unroll
        for (int j = 0; j < 8; ++j) acc[r][j] = 0.f;

    #pragma unroll 4
    for (int kk2 = 0; kk2 < C_IN / 2; ++kk2) {
        float w0[8], w1[8];
        #pragma unroll
        for (int j = 0; j < 8; ++j) {
            w0[j] = sW[2 * kk2 + 0][tx + 16 * j];   // 16 consecutive banks, 4x broadcast
            w1[j] = sW[2 * kk2 + 1][tx + 16 * j];
        }
        float f0[8], f1[8];
        #pragma unroll
        for (int r = 0; r < 8; ++r) {
            unsigned int u = *(const unsigned int*)&sF[8 * ty + r][2 * kk2];  // 4 addrs/wave, 4 distinct banks
            f0[r] = __uint_as_float(u << 16);
            f1[r] = __uint_as_float(u & 0xFFFF0000u);
        }
        #pragma unroll
        for (int r = 0; r < 8; ++r)
            #pragma unroll
            for (int j = 0; j < 8; ++j) {
                acc[r][j] = fmaf(f0[r], w0[j], acc[r][j]);
                acc[r][j] = fmaf(f1[r], w1[j], acc[r][j]);
            }
    }

    // Scatter-add: per row, 16 lanes cover 128 cols in 16-strided groups -> coalesced atomics.
    #pragma unroll
    for (int r = 0; r < 8; ++r) {
        int orow = out_idx[(size_t)k * P + p0 + 8 * ty + r];
        float* op = out + (size_t)orow * C_OUT + tx;
        #pragma unroll
        for (int j = 0; j < 8; ++j)
            atomicAdd(op + 16 * j, acc[r][j]);
    }
}

// ---------------------------------------------------------------------------
// Kernel 2: per-channel sum / sumsq over out [n_out x 128]. float4 loads.
// ---------------------------------------------------------------------------
__global__ __launch_bounds__(256) void bn_stats_kernel(
    const float* __restrict__ out, float* __restrict__ stats, int n_out)
{
    const int tid = threadIdx.x;
    const int c4   = tid & 31;   // float4 index within a row (32*4 = 128 ch)
    const int rgrp = tid >> 5;   // 8 rows per block-iteration

    float4 s  = make_float4(0.f, 0.f, 0.f, 0.f);
    float4 s2 = make_float4(0.f, 0.f, 0.f, 0.f);
    for (int r = blockIdx.x * 8 + rgrp; r < n_out; r += gridDim.x * 8) {
        float4 v = ((const float4*)(out + (size_t)r * C_OUT))[c4];
        s.x += v.x; s.y += v.y; s.z += v.z; s.w += v.w;
        s2.x += v.x * v.x; s2.y += v.y * v.y; s2.z += v.z * v.z; s2.w += v.w * v.w;
    }

    __shared__ float4 red[256], red2[256];
    red[tid] = s; red2[tid] = s2;
    __syncthreads();
    if (tid < 32) {
        #pragma unroll
        for (int j = 1; j < 8; ++j) {
            float4 a = red[tid + 32 * j], b = red2[tid + 32 * j];
            s.x += a.x; s.y += a.y; s.z += a.z; s.w += a.w;
            s2.x += b.x; s2.y += b.y; s2.z += b.z; s2.w += b.w;
        }
        atomicAdd(&stats[4 * tid + 0], s.x);
        atomicAdd(&stats[4 * tid + 1], s.y);
        atomicAdd(&stats[4 * tid + 2], s.z);
        atomicAdd(&stats[4 * tid + 3], s.w);
        atomicAdd(&stats[C_OUT + 4 * tid + 0], s2.x);
        atomicAdd(&stats[C_OUT + 4 * tid + 1], s2.y);
        atomicAdd(&stats[C_OUT + 4 * tid + 2], s2.z);
        atomicAdd(&stats[C_OUT + 4 * tid + 3], s2.w);
    }
}

// ---------------------------------------------------------------------------
// Kernel 3: normalize + LeakyReLU, in place. float4 grid-stride.
// ---------------------------------------------------------------------------
__global__ __launch_bounds__(256) void bn_apply_kernel(
    float* __restrict__ out, const float* __restrict__ stats,
    const float* __restrict__ gamma, const float* __restrict__ beta,
    int n_out, float inv_n)
{
    const size_t total = (size_t)n_out * (C_OUT / 4);
    size_t i = (size_t)blockIdx.x * 256 + threadIdx.x;
    const int c = (int)(i & 31) * 4;   // channel base; invariant (stride % 32 == 0)

    float4 sc, sh;
    {
        float m0 = stats[c + 0] * inv_n, m1 = stats[c + 1] * inv_n,
              m2 = stats[c + 2] * inv_n, m3 = stats[c + 3] * inv_n;
        float v0 = stats[C_OUT + c + 0] * inv_n - m0 * m0;
        float v1 = stats[C_OUT + c + 1] * inv_n - m1 * m1;
        float v2 = stats[C_OUT + c + 2] * inv_n - m2 * m2;
        float v3 = stats[C_OUT + c + 3] * inv_n - m3 * m3;
        sc.x = gamma[c + 0] * rsqrtf(v0 + BN_EPS);
        sc.y = gamma[c + 1] * rsqrtf(v1 + BN_EPS);
        sc.z = gamma[c + 2] * rsqrtf(v2 + BN_EPS);
        sc.w = gamma[c + 3] * rsqrtf(v3 + BN_EPS);
        sh.x = beta[c + 0] - m0 * sc.x;
        sh.y = beta[c + 1] - m1 * sc.y;
        sh.z = beta[c + 2] - m2 * sc.z;
        sh.w = beta[c + 3] - m3 * sc.w;
    }

    float4* o4 = (float4*)out;
    for (; i < total; i += (size_t)gridDim.x * 256) {
        float4 v = o4[i];
        v.x = v.x * sc.x + sh.x; v.x = v.x >= 0.f ? v.x : LEAK * v.x;
        v.y = v.y * sc.y + sh.y; v.y = v.y >= 0.f ? v.y : LEAK * v.y;
        v.z = v.z * sc.z + sh.z; v.z = v.z >= 0.f ? v.z : LEAK * v.z;
        v.w = v.w * sc.w + sh.w; v.w = v.w >= 0.f ? v.w : LEAK * v.w;
        o4[i] = v;
    }
}

// ---------------------------------------------------------------------------
extern "C" void kernel_launch(void* const* d_in, const int* in_sizes, int n_in,
                              void* d_out, int out_size, void* d_ws, size_t ws_size,
                              hipStream_t stream)
{
    const float* feats  = (const float*)d_in[0];
    const float* W      = (const float*)d_in[1];
    const float* gamma  = (const float*)d_in[2];
    const float* beta   = (const float*)d_in[3];
    const int*  in_idx  = (const int*)d_in[4];
    const int*  out_idx = (const int*)d_in[5];

    const int P     = in_sizes[4] / KOFF;     // 262144
    const int n_out = out_size / C_OUT;       // 262144
    float* out   = (float*)d_out;
    float* stats = (float*)d_ws;              // 256 floats: sum[128], sumsq[128]

    hipMemsetAsync(d_out, 0, (size_t)out_size * sizeof(float), stream);
    hipMemsetAsync(d_ws, 0, 2 * C_OUT * sizeof(float), stream);

    dim3 grid_g(P / TILE_P, KOFF);            // 2048 x 4
    scatter_gemm_kernel<<<grid_g, 256, 0, stream>>>(feats, W, in_idx, out_idx, out, P);
    bn_stats_kernel<<<2048, 256, 0, stream>>>(out, stats, n_out);
    bn_apply_kernel<<<2048, 256, 0, stream>>>(out, stats, gamma, beta, n_out, 1.0f / n_out);
}

// Round 3
// 783.128 us; speedup vs baseline: 1.4071x; 1.4071x over previous
//
#include <hip/hip_runtime.h>
#include <hip/hip_fp16.h>

// SparseConvolutionDownsample: rulebook sparse conv (gather -> GEMM -> scatter-add)
// + BatchNorm over active sites + LeakyReLU(0.333).
//
// Constants: C_IN=64, C_OUT=128, K=4, P=262144, n_out=262144.
//
// R3: scatter-add via packed f16 atomics (global_atomic_pk_add_f16) into a
// __half2 accumulator in d_ws -> half the atomic ops (R2 showed occupancy up
// 52% with dur -3% => atomic-throughput-bound, 244 G ops/s). BN reads half.
// Fallback to the R2 fp32 path if ws_size is too small.

#define C_IN   64
#define C_OUT  128
#define KOFF   4
#define TILE_P 128
#define SF_LD  66            // bf16 elems/row: 132B stride
#define BN_EPS 1e-4f
#define LEAK   0.333f

__device__ inline unsigned short f32_to_bf16_rn(float x) {
    unsigned int b = __float_as_uint(x);
    unsigned int r = (b + 0x7FFFu + ((b >> 16) & 1u)) >> 16;
    return (unsigned short)r;
}

struct h2pair { __half2 a, b; };   // 8 B = 4 channels

// ===========================================================================
// HALF-ACCUMULATOR PATH
// ===========================================================================

// Kernel 1h: gather + 128x128 GEMM tile + pk_add_f16 scatter.
// tx = tid&15 -> col pairs {2tx+32j, 2tx+1+32j} j=0..3; ty = tid>>4 -> rows 8ty..8ty+7.
__global__ __launch_bounds__(256) void scatter_gemm_half_kernel(
    const float* __restrict__ feats, const float* __restrict__ W,
    const int* __restrict__ in_idx, const int* __restrict__ out_idx,
    __half2* __restrict__ outh, int P)
{
    __shared__ float sW[C_IN][C_OUT];              // 32 KB
    __shared__ unsigned short sF[TILE_P][SF_LD];   // 16.9 KB bf16

    const int tid = threadIdx.x;
    const int k  = blockIdx.y;
    const int p0 = blockIdx.x * TILE_P;

    const float4* Wk4 = (const float4*)(W + (size_t)k * C_IN * C_OUT);
    float4* sW4 = (float4*)&sW[0][0];
    #pragma unroll
    for (int i = tid; i < C_IN * C_OUT / 4; i += 256)
        sW4[i] = Wk4[i];

    for (int i = tid; i < TILE_P * (C_IN / 4); i += 256) {
        int r  = i >> 4;
        int c4 = i & 15;
        int src = in_idx[(size_t)k * P + p0 + r];
        float4 v = ((const float4*)(feats + (size_t)src * C_IN))[c4];
        unsigned int lo = (unsigned int)f32_to_bf16_rn(v.x) | ((unsigned int)f32_to_bf16_rn(v.y) << 16);
        unsigned int hi = (unsigned int)f32_to_bf16_rn(v.z) | ((unsigned int)f32_to_bf16_rn(v.w) << 16);
        unsigned int* dst = (unsigned int*)&sF[r][c4 * 4];
        dst[0] = lo;
        dst[1] = hi;
    }
    __syncthreads();

    const int tx = tid & 15;
    const int ty = tid >> 4;

    float acc[8][8];   // acc[r][2*j2 + b] -> col 2*tx + 32*j2 + b
    #pragma unroll
    for (int r = 0; r < 8; ++r)
        #pragma unroll
        for (int j = 0; j < 8; ++j) acc[r][j] = 0.f;

    #pragma unroll 4
    for (int kk2 = 0; kk2 < C_IN / 2; ++kk2) {
        float w0[8], w1[8];
        #pragma unroll
        for (int j2 = 0; j2 < 4; ++j2) {
            float2 a = *(const float2*)&sW[2 * kk2 + 0][2 * tx + 32 * j2];  // ds_read_b64
            float2 b = *(const float2*)&sW[2 * kk2 + 1][2 * tx + 32 * j2];
            w0[2 * j2] = a.x; w0[2 * j2 + 1] = a.y;
            w1[2 * j2] = b.x; w1[2 * j2 + 1] = b.y;
        }
        float f0[8], f1[8];
        #pragma unroll
        for (int r = 0; r < 8; ++r) {
            unsigned int u = *(const unsigned int*)&sF[8 * ty + r][2 * kk2];
            f0[r] = __uint_as_float(u << 16);
            f1[r] = __uint_as_float(u & 0xFFFF0000u);
        }
        #pragma unroll
        for (int r = 0; r < 8; ++r)
            #pragma unroll
            for (int j = 0; j < 8; ++j) {
                acc[r][j] = fmaf(f0[r], w0[j], acc[r][j]);
                acc[r][j] = fmaf(f1[r], w1[j], acc[r][j]);
            }
    }

    // Packed-f16 scatter-add: 4 atomic instrs per row; lanes 0-15 cover 64B lines.
    #pragma unroll
    for (int r = 0; r < 8; ++r) {
        int orow = out_idx[(size_t)k * P + p0 + 8 * ty + r];
        __half2* op = outh + (size_t)orow * (C_OUT / 2) + tx;
        #pragma unroll
        for (int j2 = 0; j2 < 4; ++j2)
            unsafeAtomicAdd(op + 16 * j2,
                            __floats2half2_rn(acc[r][2 * j2], acc[r][2 * j2 + 1]));
    }
}

// Kernel 2h: per-channel sum/sumsq over half accumulator.
__global__ __launch_bounds__(256) void bn_stats_half_kernel(
    const __half2* __restrict__ outh, float* __restrict__ stats, int n_out)
{
    const int tid = threadIdx.x;
    const int c4   = tid & 31;   // channels 4*c4 .. 4*c4+3
    const int rgrp = tid >> 5;   // 8 rows per block-iteration

    float4 s  = make_float4(0.f, 0.f, 0.f, 0.f);
    float4 s2 = make_float4(0.f, 0.f, 0.f, 0.f);
    for (int r = blockIdx.x * 8 + rgrp; r < n_out; r += gridDim.x * 8) {
        h2pair u = ((const h2pair*)(outh + (size_t)r * (C_OUT / 2)))[c4];
        float2 fa = __half22float2(u.a), fb = __half22float2(u.b);
        s.x += fa.x; s.y += fa.y; s.z += fb.x; s.w += fb.y;
        s2.x += fa.x * fa.x; s2.y += fa.y * fa.y; s2.z += fb.x * fb.x; s2.w += fb.y * fb.y;
    }

    __shared__ float4 red[256], red2[256];
    red[tid] = s; red2[tid] = s2;
    __syncthreads();
    if (tid < 32) {
        #pragma unroll
        for (int j = 1; j < 8; ++j) {
            float4 a = red[tid + 32 * j], b = red2[tid + 32 * j];
            s.x += a.x; s.y += a.y; s.z += a.z; s.w += a.w;
            s2.x += b.x; s2.y += b.y; s2.z += b.z; s2.w += b.w;
        }
        atomicAdd(&stats[4 * tid + 0], s.x);
        atomicAdd(&stats[4 * tid + 1], s.y);
        atomicAdd(&stats[4 * tid + 2], s.z);
        atomicAdd(&stats[4 * tid + 3], s.w);
        atomicAdd(&stats[C_OUT + 4 * tid + 0], s2.x);
        atomicAdd(&stats[C_OUT + 4 * tid + 1], s2.y);
        atomicAdd(&stats[C_OUT + 4 * tid + 2], s2.z);
        atomicAdd(&stats[C_OUT + 4 * tid + 3], s2.w);
    }
}

// Kernel 3h: normalize + LeakyReLU, half in -> fp32 out.
__global__ __launch_bounds__(256) void bn_apply_half_kernel(
    const __half2* __restrict__ outh, float* __restrict__ out,
    const float* __restrict__ stats,
    const float* __restrict__ gamma, const float* __restrict__ beta,
    int n_out, float inv_n)
{
    const size_t total = (size_t)n_out * (C_OUT / 4);   // h2pair units
    size_t i = (size_t)blockIdx.x * 256 + threadIdx.x;
    const int c = (int)(i & 31) * 4;

    float4 sc, sh;
    {
        float m0 = stats[c + 0] * inv_n, m1 = stats[c + 1] * inv_n,
              m2 = stats[c + 2] * inv_n, m3 = stats[c + 3] * inv_n;
        float v0 = stats[C_OUT + c + 0] * inv_n - m0 * m0;
        float v1 = stats[C_OUT + c + 1] * inv_n - m1 * m1;
        float v2 = stats[C_OUT + c + 2] * inv_n - m2 * m2;
        float v3 = stats[C_OUT + c + 3] * inv_n - m3 * m3;
        sc.x = gamma[c + 0] * rsqrtf(v0 + BN_EPS);
        sc.y = gamma[c + 1] * rsqrtf(v1 + BN_EPS);
        sc.z = gamma[c + 2] * rsqrtf(v2 + BN_EPS);
        sc.w = gamma[c + 3] * rsqrtf(v3 + BN_EPS);
        sh.x = beta[c + 0] - m0 * sc.x;
        sh.y = beta[c + 1] - m1 * sc.y;
        sh.z = beta[c + 2] - m2 * sc.z;
        sh.w = beta[c + 3] - m3 * sc.w;
    }

    const h2pair* ih = (const h2pair*)outh;
    float4* o4 = (float4*)out;
    for (; i < total; i += (size_t)gridDim.x * 256) {
        h2pair u = ih[i];
        float2 fa = __half22float2(u.a), fb = __half22float2(u.b);
        float4 v = make_float4(fa.x, fa.y, fb.x, fb.y);
        v.x = v.x * sc.x + sh.x; v.x = v.x >= 0.f ? v.x : LEAK * v.x;
        v.y = v.y * sc.y + sh.y; v.y = v.y >= 0.f ? v.y : LEAK * v.y;
        v.z = v.z * sc.z + sh.z; v.z = v.z >= 0.f ? v.z : LEAK * v.z;
        v.w = v.w * sc.w + sh.w; v.w = v.w >= 0.f ? v.w : LEAK * v.w;
        o4[i] = v;
    }
}

// ===========================================================================
// FP32 FALLBACK PATH (R2, unchanged) — used if ws_size too small
// ===========================================================================

__global__ __launch_bounds__(256) void scatter_gemm_f32_kernel(
    const float* __restrict__ feats, const float* __restrict__ W,
    const int* __restrict__ in_idx, const int* __restrict__ out_idx,
    float* __restrict__ out, int P)
{
    __shared__ float sW[C_IN][C_OUT];
    __shared__ unsigned short sF[TILE_P][SF_LD];

    const int tid = threadIdx.x;
    const int k  = blockIdx.y;
    const int p0 = blockIdx.x * TILE_P;

    const float4* Wk4 = (const float4*)(W + (size_t)k * C_IN * C_OUT);
    float4* sW4 = (float4*)&sW[0][0];
    #pragma unroll
    for (int i = tid; i < C_IN * C_OUT / 4; i += 256)
        sW4[i] = Wk4[i];

    for (int i = tid; i < TILE_P * (C_IN / 4); i += 256) {
        int r  = i >> 4;
        int c4 = i & 15;
        int src = in_idx[(size_t)k * P + p0 + r];
        float4 v = ((const float4*)(feats + (size_t)src * C_IN))[c4];
        unsigned int lo = (unsigned int)f32_to_bf16_rn(v.x) | ((unsigned int)f32_to_bf16_rn(v.y) << 16);
        unsigned int hi = (unsigned int)f32_to_bf16_rn(v.z) | ((unsigned int)f32_to_bf16_rn(v.w) << 16);
        unsigned int* dst = (unsigned int*)&sF[r][c4 * 4];
        dst[0] = lo;
        dst[1] = hi;
    }
    __syncthreads();

    const int tx = tid & 15;
    const int ty = tid >> 4;

    float acc[8][8];
    #pragma unroll
    for (int r = 0; r < 8; ++r)
        #pragma unroll
        for (int j = 0; j < 8; ++j) acc[r][j] = 0.f;

    #pragma unroll 4
    for (int kk2 = 0; kk2 < C_IN / 2; ++kk2) {
        float w0[8], w1[8];
        #pragma unroll
        for (int j = 0; j < 8; ++j) {
            w0[j] = sW[2 * kk2 + 0][tx + 16 * j];
            w1[j] = sW[2 * kk2 + 1][tx + 16 * j];
        }
        float f0[8], f1[8];
        #pragma unroll
        for (int r = 0; r < 8; ++r) {
            unsigned int u = *(const unsigned int*)&sF[8 * ty + r][2 * kk2];
            f0[r] = __uint_as_float(u << 16);
            f1[r] = __uint_as_float(u & 0xFFFF0000u);
        }
        #pragma unroll
        for (int r = 0; r < 8; ++r)
            #pragma unroll
            for (int j = 0; j < 8; ++j) {
                acc[r][j] = fmaf(f0[r], w0[j], acc[r][j]);
                acc[r][j] = fmaf(f1[r], w1[j], acc[r][j]);
            }
    }

    #pragma unroll
    for (int r = 0; r < 8; ++r) {
        int orow = out_idx[(size_t)k * P + p0 + 8 * ty + r];
        float* op = out + (size_t)orow * C_OUT + tx;
        #pragma unroll
        for (int j = 0; j < 8; ++j)
            atomicAdd(op + 16 * j, acc[r][j]);
    }
}

__global__ __launch_bounds__(256) void bn_stats_f32_kernel(
    const float* __restrict__ out, float* __restrict__ stats, int n_out)
{
    const int tid = threadIdx.x;
    const int c4   = tid & 31;
    const int rgrp = tid >> 5;

    float4 s  = make_float4(0.f, 0.f, 0.f, 0.f);
    float4 s2 = make_float4(0.f, 0.f, 0.f, 0.f);
    for (int r = blockIdx.x * 8 + rgrp; r < n_out; r += gridDim.x * 8) {
        float4 v = ((const float4*)(out + (size_t)r * C_OUT))[c4];
        s.x += v.x; s.y += v.y; s.z += v.z; s.w += v.w;
        s2.x += v.x * v.x; s2.y += v.y * v.y; s2.z += v.z * v.z; s2.w += v.w * v.w;
    }

    __shared__ float4 red[256], red2[256];
    red[tid] = s; red2[tid] = s2;
    __syncthreads();
    if (tid < 32) {
        #pragma unroll
        for (int j = 1; j < 8; ++j) {
            float4 a = red[tid + 32 * j], b = red2[tid + 32 * j];
            s.x += a.x; s.y += a.y; s.z += a.z; s.w += a.w;
            s2.x += b.x; s2.y += b.y; s2.z += b.z; s2.w += b.w;
        }
        atomicAdd(&stats[4 * tid + 0], s.x);
        atomicAdd(&stats[4 * tid + 1], s.y);
        atomicAdd(&stats[4 * tid + 2], s.z);
        atomicAdd(&stats[4 * tid + 3], s.w);
        atomicAdd(&stats[C_OUT + 4 * tid + 0], s2.x);
        atomicAdd(&stats[C_OUT + 4 * tid + 1], s2.y);
        atomicAdd(&stats[C_OUT + 4 * tid + 2], s2.z);
        atomicAdd(&stats[C_OUT + 4 * tid + 3], s2.w);
    }
}

__global__ __launch_bounds__(256) void bn_apply_f32_kernel(
    float* __restrict__ out, const float* __restrict__ stats,
    const float* __restrict__ gamma, const float* __restrict__ beta,
    int n_out, float inv_n)
{
    const size_t total = (size_t)n_out * (C_OUT / 4);
    size_t i = (size_t)blockIdx.x * 256 + threadIdx.x;
    const int c = (int)(i & 31) * 4;

    float4 sc, sh;
    {
        float m0 = stats[c + 0] * inv_n, m1 = stats[c + 1] * inv_n,
              m2 = stats[c + 2] * inv_n, m3 = stats[c + 3] * inv_n;
        float v0 = stats[C_OUT + c + 0] * inv_n - m0 * m0;
        float v1 = stats[C_OUT + c + 1] * inv_n - m1 * m1;
        float v2 = stats[C_OUT + c + 2] * inv_n - m2 * m2;
        float v3 = stats[C_OUT + c + 3] * inv_n - m3 * m3;
        sc.x = gamma[c + 0] * rsqrtf(v0 + BN_EPS);
        sc.y = gamma[c + 1] * rsqrtf(v1 + BN_EPS);
        sc.z = gamma[c + 2] * rsqrtf(v2 + BN_EPS);
        sc.w = gamma[c + 3] * rsqrtf(v3 + BN_EPS);
        sh.x = beta[c + 0] - m0 * sc.x;
        sh.y = beta[c + 1] - m1 * sc.y;
        sh.z = beta[c + 2] - m2 * sc.z;
        sh.w = beta[c + 3] - m3 * sc.w;
    }

    float4* o4 = (float4*)out;
    for (; i < total; i += (size_t)gridDim.x * 256) {
        float4 v = o4[i];
        v.x = v.x * sc.x + sh.x; v.x = v.x >= 0.f ? v.x : LEAK * v.x;
        v.y = v.y * sc.y + sh.y; v.y = v.y >= 0.f ? v.y : LEAK * v.y;
        v.z = v.z * sc.z + sh.z; v.z = v.z >= 0.f ? v.z : LEAK * v.z;
        v.w = v.w * sc.w + sh.w; v.w = v.w >= 0.f ? v.w : LEAK * v.w;
        o4[i] = v;
    }
}

// ---------------------------------------------------------------------------
extern "C" void kernel_launch(void* const* d_in, const int* in_sizes, int n_in,
                              void* d_out, int out_size, void* d_ws, size_t ws_size,
                              hipStream_t stream)
{
    const float* feats  = (const float*)d_in[0];
    const float* W      = (const float*)d_in[1];
    const float* gamma  = (const float*)d_in[2];
    const float* beta   = (const float*)d_in[3];
    const int*  in_idx  = (const int*)d_in[4];
    const int*  out_idx = (const int*)d_in[5];

    const int P     = in_sizes[4] / KOFF;     // 262144
    const int n_out = out_size / C_OUT;       // 262144

    dim3 grid_g(P / TILE_P, KOFF);            // 2048 x 4

    const size_t half_bytes = (size_t)n_out * C_OUT * sizeof(__half);   // 67 MB

    if (ws_size >= half_bytes + 1024) {
        __half2* outh = (__half2*)d_ws;
        float* stats = (float*)((char*)d_ws + half_bytes);
        hipMemsetAsync(d_ws, 0, half_bytes, stream);
        hipMemsetAsync(stats, 0, 2 * C_OUT * sizeof(float), stream);

        scatter_gemm_half_kernel<<<grid_g, 256, 0, stream>>>(feats, W, in_idx, out_idx, outh, P);
        bn_stats_half_kernel<<<1024, 256, 0, stream>>>(outh, stats, n_out);
        bn_apply_half_kernel<<<2048, 256, 0, stream>>>(outh, (float*)d_out, stats,
                                                       gamma, beta, n_out, 1.0f / n_out);
    } else {
        float* out   = (float*)d_out;
        float* stats = (float*)d_ws;
        hipMemsetAsync(d_out, 0, (size_t)out_size * sizeof(float), stream);
        hipMemsetAsync(d_ws, 0, 2 * C_OUT * sizeof(float), stream);

        scatter_gemm_f32_kernel<<<grid_g, 256, 0, stream>>>(feats, W, in_idx, out_idx, out, P);
        bn_stats_f32_kernel<<<1024, 256, 0, stream>>>(out, stats, n_out);
        bn_apply_f32_kernel<<<2048, 256, 0, stream>>>(out, stats, gamma, beta, n_out, 1.0f / n_out);
    }
}